// Round 1
// baseline (805.361 us; speedup 1.0000x reference)
//
#include <hip/hip_runtime.h>
#include <math.h>

#define NB 4
#define NH 32
#define NSQ 2048            // seq len
#define ND 128              // head dim
#define SPLIT 2
#define SCHUNK (NSQ / SPLIT)   // 1024
#define RB 64                  // rows per block-iteration
#define NITER (SCHUNK / RB)    // 16
#define NTHR 512
#define PAD_F4 33              // float4 row stride of lsq/lsk (132 floats)

static constexpr size_t OUT_ELEMS = (size_t)NB * NH * NSQ * ND;        // 33554432
static constexpr size_t NS_OFF    = OUT_ELEMS;                         // new_states
static constexpr size_t NZ_OFF    = NS_OFF + (size_t)NB * NH * ND * ND; // new_z
// LDS: lmem 4096 f4 | lsq 64*33 f4 | lsk 64*33 f4 | lz 32 f4 | lgate 32 f4 | lsqz 64 f | lskz 64 f | lnz 128 f
static constexpr int LDS_F4    = ND * ND / 4 + 2 * RB * PAD_F4 + ND / 4 + ND / 4; // 8384
static constexpr int LDS_BYTES = LDS_F4 * 16 + (RB + RB + ND) * 4;                // 135168

__device__ __forceinline__ float4 f4fma(float a, float4 b, float4 c) {
    float4 r;
    r.x = fmaf(a, b.x, c.x); r.y = fmaf(a, b.y, c.y);
    r.z = fmaf(a, b.z, c.z); r.w = fmaf(a, b.w, c.w);
    return r;
}

__device__ __forceinline__ float4 elu1(float4 x) {
    // elu(x)+1 : x>0 -> x+1 ; x<=0 -> exp(x)
    float4 r;
    r.x = x.x > 0.f ? x.x + 1.f : __expf(x.x);
    r.y = x.y > 0.f ? x.y + 1.f : __expf(x.y);
    r.z = x.z > 0.f ? x.z + 1.f : __expf(x.z);
    r.w = x.w > 0.f ? x.w + 1.f : __expf(x.w);
    return r;
}

// Pre-init new_states = broadcast(init_mem), new_z = broadcast(init_z); main kernel atomicAdds partials.
extern "C" __global__ void cm_init(const float* __restrict__ mem0,
                                   const float* __restrict__ z0,
                                   float* __restrict__ out) {
    const int NSF4 = NB * NH * ND * ND / 4;  // 524288
    const int NZF4 = NB * NH * ND / 4;       // 4096
    int idx = blockIdx.x * 256 + threadIdx.x;
    if (idx < NSF4) {
        const int per_bh = ND * ND / 4;      // 4096
        int h = (idx / per_bh) % NH;
        int off = idx % per_bh;
        ((float4*)(out + NS_OFF))[idx] = ((const float4*)mem0)[h * per_bh + off];
    } else if (idx < NSF4 + NZF4) {
        int j = idx - NSF4;
        const int per_bh = ND / 4;           // 32
        int h = (j / per_bh) % NH;
        int off = j % per_bh;
        ((float4*)(out + NZ_OFF))[j] = ((const float4*)z0)[h * per_bh + off];
    }
}

extern "C" __global__ void __launch_bounds__(NTHR, 2)
cm_main(const float* __restrict__ q, const float* __restrict__ kin,
        const float* __restrict__ v, const float* __restrict__ attn,
        const float* __restrict__ betas, const float* __restrict__ mem0,
        const float* __restrict__ z0, float* __restrict__ out) {
    extern __shared__ float lds[];
    float4* lmem4  = (float4*)lds;                 // [128][32] f4, row-major mem[i][j]
    float4* lsq4   = lmem4 + ND * ND / 4;          // [64][PAD_F4] f4 (reused as vd)
    float4* lsk4   = lsq4 + RB * PAD_F4;           // [64][PAD_F4] f4
    float4* lz4    = lsk4 + RB * PAD_F4;           // [32] f4
    float4* lgate4 = lz4 + ND / 4;                 // [32] f4
    float*  lsqz   = (float*)(lgate4 + ND / 4);    // [64]
    float*  lskz   = lsqz + RB;                    // [64]
    float*  lnz    = lskz + RB;                    // [128]

    const int t  = threadIdx.x;
    const int wg = blockIdx.x;
    const int c  = wg % SPLIT;
    const int h  = (wg / SPLIT) % NH;
    const int b  = wg / (SPLIT * NH);

    // ---- phase 0: stage mem[h], z[h], gate[h]; zero lnz ----
    const float4* memh4 = (const float4*)(mem0 + (size_t)h * ND * ND);
    #pragma unroll
    for (int i = 0; i < (ND * ND / 4) / NTHR; ++i)   // 8
        lmem4[i * NTHR + t] = memh4[i * NTHR + t];
    if (t < ND) {
        ((float*)lz4)[t] = z0[h * ND + t];
        float be = betas[h * ND + t];
        ((float*)lgate4)[t] = 1.f / (1.f + __expf(-be));
        lnz[t] = 0.f;
    }

    const int cg = t & 31;    // column group (4 cols)
    const int rg = t >> 5;    // 0..15: row group (matvec: 4 rows) / i-group (outer: 8 rows)
    const int r0 = rg * 4;

    const size_t bh = (size_t)b * NH + h;
    const float4* q4 = (const float4*)(q    + bh * NSQ * ND);
    const float4* k4 = (const float4*)(kin  + bh * NSQ * ND);
    const float4* v4 = (const float4*)(v    + bh * NSQ * ND);
    const float4* a4 = (const float4*)(attn + bh * NSQ * ND);
    float4*       o4 = (float4*)      (out  + bh * NSQ * ND);

    float4 nsacc[8];
    #pragma unroll
    for (int i = 0; i < 8; ++i) nsacc[i] = make_float4(0.f, 0.f, 0.f, 0.f);
    float4 nz = make_float4(0.f, 0.f, 0.f, 0.f);

    __syncthreads();

    for (int blk = 0; blk < NITER; ++blk) {
        const int s0 = c * SCHUNK + blk * RB;

        // ---- stage sigma_q, sigma_k (64 rows x 128 cols each) ----
        #pragma unroll
        for (int m = 0; m < 4; ++m) {
            int fi   = m * NTHR + t;       // 0..2047
            int row  = fi >> 5;            // 0..63
            int col4 = fi & 31;            // == t & 31
            size_t g = (size_t)(s0 + row) * 32 + col4;
            float4 sq = elu1(q4[g]);
            lsq4[row * PAD_F4 + col4] = sq;
            float4 sk = elu1(k4[g]);
            lsk4[row * PAD_F4 + col4] = sk;
            nz.x += sk.x; nz.y += sk.y; nz.z += sk.z; nz.w += sk.w;
        }
        __syncthreads();

        // ---- z-dots on waves 0-1 (overlapped with other waves' matvec) ----
        if (t < 2 * RB) {
            int r = t & (RB - 1);
            const float4* src = (t < RB) ? lsq4 : lsk4;
            float4 acc = make_float4(0.f, 0.f, 0.f, 0.f);
            #pragma unroll 8
            for (int d4 = 0; d4 < 32; ++d4) {
                float4 a = src[r * PAD_F4 + d4];
                float4 z = lz4[d4];
                acc.x = fmaf(a.x, z.x, acc.x);
                acc.y = fmaf(a.y, z.y, acc.y);
                acc.z = fmaf(a.z, z.z, acc.z);
                acc.w = fmaf(a.w, z.w, acc.w);
            }
            float dv = acc.x + acc.y + acc.z + acc.w;
            if (t < RB) lsqz[r] = dv; else lskz[r] = dv;
        }

        // ---- matvec: mo = sq @ mem, rt = sk @ mem (4 rows x 4 cols per thread) ----
        float4 mo[4], rt[4];
        #pragma unroll
        for (int rr = 0; rr < 4; ++rr) {
            mo[rr] = make_float4(0.f, 0.f, 0.f, 0.f);
            rt[rr] = make_float4(0.f, 0.f, 0.f, 0.f);
        }
        #pragma unroll 4
        for (int i4 = 0; i4 < 32; ++i4) {
            float4 m[4];
            #pragma unroll
            for (int ii = 0; ii < 4; ++ii)
                m[ii] = lmem4[(i4 * 4 + ii) * 32 + cg];
            #pragma unroll
            for (int rr = 0; rr < 4; ++rr) {
                float4 sq = lsq4[(r0 + rr) * PAD_F4 + i4];
                float4 sk = lsk4[(r0 + rr) * PAD_F4 + i4];
                mo[rr] = f4fma(sq.x, m[0], mo[rr]);
                mo[rr] = f4fma(sq.y, m[1], mo[rr]);
                mo[rr] = f4fma(sq.z, m[2], mo[rr]);
                mo[rr] = f4fma(sq.w, m[3], mo[rr]);
                rt[rr] = f4fma(sk.x, m[0], rt[rr]);
                rt[rr] = f4fma(sk.y, m[1], rt[rr]);
                rt[rr] = f4fma(sk.z, m[2], rt[rr]);
                rt[rr] = f4fma(sk.w, m[3], rt[rr]);
            }
        }
        __syncthreads();   // z-dots written, all lsq/lsk matvec reads done

        // ---- epilogue: out = gate*mo/sqz + (1-gate)*attn ; vd = v - rt/skz -> lsq ----
        float4 g = lgate4[cg];
        #pragma unroll
        for (int rr = 0; rr < 4; ++rr) {
            int r = r0 + rr;
            size_t row4 = (size_t)(s0 + r) * 32 + cg;
            float4 av = a4[row4];
            float4 vv = v4[row4];
            float isq = 1.f / lsqz[r];
            float isk = 1.f / lskz[r];
            float4 o;
            o.x = fmaf(g.x, fmaf(mo[rr].x, isq, -av.x), av.x);
            o.y = fmaf(g.y, fmaf(mo[rr].y, isq, -av.y), av.y);
            o.z = fmaf(g.z, fmaf(mo[rr].z, isq, -av.z), av.z);
            o.w = fmaf(g.w, fmaf(mo[rr].w, isq, -av.w), av.w);
            o4[row4] = o;
            float4 vd;
            vd.x = fmaf(-isk, rt[rr].x, vv.x);
            vd.y = fmaf(-isk, rt[rr].y, vv.y);
            vd.z = fmaf(-isk, rt[rr].z, vv.z);
            vd.w = fmaf(-isk, rt[rr].w, vv.w);
            lsq4[r * PAD_F4 + cg] = vd;   // vd overwrites sq buffer
        }
        __syncthreads();

        // ---- outer product: ns[i][j] += sum_r sk[r][i] * vd[r][j] (8 i x 4 j per thread) ----
        #pragma unroll 2
        for (int r = 0; r < RB; ++r) {
            float4 ska = lsk4[r * PAD_F4 + rg * 2];
            float4 skb = lsk4[r * PAD_F4 + rg * 2 + 1];
            float4 vd  = lsq4[r * PAD_F4 + cg];
            nsacc[0] = f4fma(ska.x, vd, nsacc[0]);
            nsacc[1] = f4fma(ska.y, vd, nsacc[1]);
            nsacc[2] = f4fma(ska.z, vd, nsacc[2]);
            nsacc[3] = f4fma(ska.w, vd, nsacc[3]);
            nsacc[4] = f4fma(skb.x, vd, nsacc[4]);
            nsacc[5] = f4fma(skb.y, vd, nsacc[5]);
            nsacc[6] = f4fma(skb.z, vd, nsacc[6]);
            nsacc[7] = f4fma(skb.w, vd, nsacc[7]);
        }
        __syncthreads();   // protect lsq/lsk for next stage
    }

    // ---- writeback new_states partials ----
    float* nso = out + NS_OFF + bh * ND * ND;
    #pragma unroll
    for (int ii = 0; ii < 8; ++ii) {
        int i = rg * 8 + ii;
        float* p = nso + i * ND + cg * 4;
        atomicAdd(p + 0, nsacc[ii].x);
        atomicAdd(p + 1, nsacc[ii].y);
        atomicAdd(p + 2, nsacc[ii].z);
        atomicAdd(p + 3, nsacc[ii].w);
    }
    // ---- writeback new_z partials ----
    atomicAdd(&lnz[cg * 4 + 0], nz.x);
    atomicAdd(&lnz[cg * 4 + 1], nz.y);
    atomicAdd(&lnz[cg * 4 + 2], nz.z);
    atomicAdd(&lnz[cg * 4 + 3], nz.w);
    __syncthreads();
    if (t < ND) atomicAdd(out + NZ_OFF + bh * ND + t, lnz[t]);
}

extern "C" void kernel_launch(void* const* d_in, const int* in_sizes, int n_in,
                              void* d_out, int out_size, void* d_ws, size_t ws_size,
                              hipStream_t stream) {
    const float* q     = (const float*)d_in[0];
    const float* k     = (const float*)d_in[1];
    const float* v     = (const float*)d_in[2];
    const float* attn  = (const float*)d_in[3];
    const float* betas = (const float*)d_in[4];
    const float* mem0  = (const float*)d_in[5];
    const float* z0    = (const float*)d_in[6];
    float* out = (float*)d_out;

    hipFuncSetAttribute((const void*)cm_main,
                        hipFuncAttributeMaxDynamicSharedMemorySize, LDS_BYTES);

    const int initF4 = NB * NH * ND * ND / 4 + NB * NH * ND / 4;  // 528384
    cm_init<<<(initF4 + 255) / 256, 256, 0, stream>>>(mem0, z0, out);
    cm_main<<<NB * NH * SPLIT, NTHR, LDS_BYTES, stream>>>(q, k, v, attn, betas, mem0, z0, out);
}